// Round 2
// baseline (935.146 us; speedup 1.0000x reference)
//
#include <hip/hip_runtime.h>

#define B_N 4096
#define C_N 128
#define E_N 10

#define NM3 165
#define NM2 45

// Usym float-offsets (relative to usym base in ws)
#define OFF_S3 0        // [165][23]
#define OFF_V3 3795     // [165][3][15]
#define OFF_S2 11220    // [45][3]
#define OFF_V2 11355    // [45][12]
#define USYM_FLOATS 11895

__device__ __forceinline__ void unrank3(int m, int& I, int& J, int& K) {
    int n = 0;
    for (int i = 0; i < 9; ++i)
        for (int j = i; j < 9; ++j)
            for (int k = j; k < 9; ++k) {
                if (n == m) { I = i; J = j; K = k; return; }
                ++n;
            }
}
__device__ __forceinline__ void unrank2(int m, int& I, int& J) {
    int n = 0;
    for (int i = 0; i < 9; ++i)
        for (int j = i; j < 9; ++j) {
            if (n == m) { I = i; J = j; return; }
            ++n;
        }
}

// ---------------------------------------------------------------------------
// Kernel 1: bucket nodes by element (y one-hot over E=10).
// ws: cnt[10] @0 (zeroed each call), list[10*4096] @ byte 64.
// ---------------------------------------------------------------------------
__global__ __launch_bounds__(256) void build_lists_kernel(
    const float* __restrict__ y, int* __restrict__ cnt, int* __restrict__ list)
{
    int b = blockIdx.x * 256 + threadIdx.x;
    if (b >= B_N) return;
    const float* yb = y + (size_t)b * E_N;
    int e = 0;
#pragma unroll
    for (int j = 1; j < E_N; ++j) e = (yb[j] > 0.5f) ? j : e;
    int pos = atomicAdd(&cnt[e], 1);
    list[e * B_N + pos] = b;
}

// ---------------------------------------------------------------------------
// Kernel 2: symmetrize U tensors into monomial basis (e,c-independent).
// Only the symmetric part of U3/U2 contributes to the polynomial.
// ---------------------------------------------------------------------------
__global__ __launch_bounds__(256) void sym_u_kernel(
    const float* __restrict__ U3s, const float* __restrict__ U2s,
    const float* __restrict__ U3v, const float* __restrict__ U2v,
    float* __restrict__ us)
{
    int t = blockIdx.x * 256 + threadIdx.x;
    if (t < 3795) {                      // S3: [165][23]
        int m = t / 23, kk = t - m * 23;
        int i, j, k; unrank3(m, i, j, k);
        float sc = (i == k) ? (1.f / 6.f) : ((i == j || j == k) ? 0.5f : 1.f);
#define U3S(a,b,cc) U3s[(((a)*9+(b))*9+(cc))*23 + kk]
        float v = U3S(i,j,k) + U3S(i,k,j) + U3S(j,i,k) + U3S(j,k,i) + U3S(k,i,j) + U3S(k,j,i);
        us[OFF_S3 + m * 23 + kk] = v * sc;
    } else if (t < 11220) {              // V3: [165][3][15]
        int r = t - 3795;
        int m = r / 45, q = r - m * 45;
        int a = q / 15, kk = q - a * 15;
        int i, j, k; unrank3(m, i, j, k);
        float sc = (i == k) ? (1.f / 6.f) : ((i == j || j == k) ? 0.5f : 1.f);
#define U3V(p,b,cc) U3v[((((a)*9+(p))*9+(b))*9+(cc))*15 + kk]
        float v = U3V(i,j,k) + U3V(i,k,j) + U3V(j,i,k) + U3V(j,k,i) + U3V(k,i,j) + U3V(k,j,i);
        us[OFF_V3 + m * 45 + a * 15 + kk] = v * sc;
    } else if (t < 11355) {              // S2: [45][3]
        int r = t - 11220;
        int m = r / 3, kk = r - m * 3;
        int i, j; unrank2(m, i, j);
        float sc = (i == j) ? 0.5f : 1.f;
        float v = (U2s[(i * 9 + j) * 3 + kk] + U2s[(j * 9 + i) * 3 + kk]) * sc;
        us[OFF_S2 + m * 3 + kk] = v;
    } else if (t < USYM_FLOATS) {        // V2: [45][12]
        int r = t - 11355;
        int m = r / 12, q = r - m * 12;
        int a = q / 4, kk = q - a * 4;
        int i, j; unrank2(m, i, j);
        float sc = (i == j) ? 0.5f : 1.f;
        float v = (U2v[((a * 9 + i) * 9 + j) * 4 + kk] + U2v[((a * 9 + j) * 9 + i) * 4 + kk]) * sc;
        us[OFF_V2 + m * 12 + a * 4 + kk] = v;
    }
}

#define FMA4(acc, t, s) { acc.x = fmaf((t).x, (s), acc.x); acc.y = fmaf((t).y, (s), acc.y); \
                          acc.z = fmaf((t).z, (s), acc.z); acc.w = fmaf((t).w, (s), acc.w); }

// ---------------------------------------------------------------------------
// Kernel 3: main contraction. Block = (channel c, element e, chunk of 512
// nodes). Build 219 float4 monomial coefficients in LDS (one ds_read_b128
// broadcast feeds 8 FMAs), each thread evaluates the degree-3 polynomial for
// 2 nodes.
// ---------------------------------------------------------------------------
__global__ __launch_bounds__(256) void sc_main_kernel(
    const float* __restrict__ x,
    const int* __restrict__ cnt, const int* __restrict__ list,
    const float* __restrict__ usym,
    const float* __restrict__ U1s, const float* __restrict__ U1v,
    const float* __restrict__ W1s, const float* __restrict__ W2s, const float* __restrict__ W3s,
    const float* __restrict__ W1v, const float* __restrict__ W2v, const float* __restrict__ W3v,
    float* __restrict__ out)
{
    const int c     = blockIdx.x;   // 0..127
    const int e     = blockIdx.y;   // 0..9
    const int chunk = blockIdx.z;   // 0..7  (512 nodes per block)

    const int n = cnt[e];
    if (chunk * 512 >= n) return;   // uniform early exit

    __shared__ float4 Tm3[NM3];
    __shared__ float4 Tm2[NM2];
    __shared__ float4 Tm1[9];

    const int tid = threadIdx.x;

    // ---- build monomial coefficient tables: Tm = sum_k Usym[m,k] * W[e,k,c]
    if (tid < NM3) {
        const int m = tid;
        float4 t;
        {
            const float* u = usym + OFF_S3 + m * 23;
            float s = 0.f;
#pragma unroll
            for (int k = 0; k < 23; ++k) s = fmaf(u[k], W3s[(e * 23 + k) * C_N + c], s);
            t.x = s;
        }
        float tv[3];
#pragma unroll
        for (int a = 0; a < 3; ++a) {
            const float* u = usym + OFF_V3 + m * 45 + a * 15;
            float s = 0.f;
#pragma unroll
            for (int k = 0; k < 15; ++k) s = fmaf(u[k], W3v[(e * 15 + k) * C_N + c], s);
            tv[a] = s;
        }
        t.y = tv[0]; t.z = tv[1]; t.w = tv[2];
        Tm3[m] = t;
    } else if (tid < NM3 + NM2) {
        const int m = tid - NM3;
        float4 t;
        {
            const float* u = usym + OFF_S2 + m * 3;
            float s = 0.f;
#pragma unroll
            for (int k = 0; k < 3; ++k) s = fmaf(u[k], W2s[(e * 3 + k) * C_N + c], s);
            t.x = s;
        }
        float tv[3];
#pragma unroll
        for (int a = 0; a < 3; ++a) {
            const float* u = usym + OFF_V2 + m * 12 + a * 4;
            float s = 0.f;
#pragma unroll
            for (int k = 0; k < 4; ++k) s = fmaf(u[k], W2v[(e * 4 + k) * C_N + c], s);
            tv[a] = s;
        }
        t.y = tv[0]; t.z = tv[1]; t.w = tv[2];
        Tm2[m] = t;
    } else if (tid < NM3 + NM2 + 9) {
        const int i = tid - (NM3 + NM2);
        float4 t;
        t.x = U1s[i]         * W1s[e * C_N + c];
        t.y = U1v[0 * 9 + i] * W1v[e * C_N + c];
        t.z = U1v[1 * 9 + i] * W1v[e * C_N + c];
        t.w = U1v[2 * 9 + i] * W1v[e * C_N + c];
        Tm1[i] = t;
    }

    __syncthreads();

    const int idx0 = chunk * 512 + tid;
    if (idx0 >= n) return;          // no barriers after this point
    const int idx1 = idx0 + 256;
    const bool p1 = idx1 < n;

    const int b0 = list[e * B_N + idx0];
    const int b1 = p1 ? list[e * B_N + idx1] : b0;

    const float* xp0 = x + ((size_t)b0 * C_N + c) * 9;
    const float* xp1 = x + ((size_t)b1 * C_N + c) * 9;
    float x0[9], x1[9];
#pragma unroll
    for (int i = 0; i < 9; ++i) { x0[i] = xp0[i]; x1[i] = xp1[i]; }

    float4 a0 = make_float4(0.f, 0.f, 0.f, 0.f);
    float4 a1 = make_float4(0.f, 0.f, 0.f, 0.f);

    // degree 1
#pragma unroll
    for (int i = 0; i < 9; ++i) {
        float4 t = Tm1[i];
        FMA4(a0, t, x0[i]);
        FMA4(a1, t, x1[i]);
    }

    // degree 2 + degree 3, triangular, fully unrolled (m2/m3 are compile-time)
    int m2 = 0, m3 = 0;
#pragma unroll
    for (int i = 0; i < 9; ++i) {
#pragma unroll
        for (int j = i; j < 9; ++j) {
            float xij0 = x0[i] * x0[j];
            float xij1 = x1[i] * x1[j];
            float4 t2 = Tm2[m2++];
            FMA4(a0, t2, xij0);
            FMA4(a1, t2, xij1);
#pragma unroll
            for (int k = j; k < 9; ++k) {
                float q0 = xij0 * x0[k];
                float q1 = xij1 * x1[k];
                float4 t3 = Tm3[m3++];
                FMA4(a0, t3, q0);
                FMA4(a1, t3, q1);
            }
        }
    }

    {
        float* o = out + (size_t)b0 * 512;
        o[c] = a0.x;
        o[128 + c * 3 + 0] = a0.y;
        o[128 + c * 3 + 1] = a0.z;
        o[128 + c * 3 + 2] = a0.w;
    }
    if (p1) {
        float* o = out + (size_t)b1 * 512;
        o[c] = a1.x;
        o[128 + c * 3 + 0] = a1.y;
        o[128 + c * 3 + 1] = a1.z;
        o[128 + c * 3 + 2] = a1.w;
    }
}

// ---------------------------------------------------------------------------
extern "C" void kernel_launch(void* const* d_in, const int* in_sizes, int n_in,
                              void* d_out, int out_size, void* d_ws, size_t ws_size,
                              hipStream_t stream) {
    const float* x   = (const float*)d_in[0];
    const float* y   = (const float*)d_in[1];
    const float* U1s = (const float*)d_in[2];
    const float* U2s = (const float*)d_in[3];
    const float* U3s = (const float*)d_in[4];
    const float* W1s = (const float*)d_in[5];
    const float* W2s = (const float*)d_in[6];
    const float* W3s = (const float*)d_in[7];
    const float* U1v = (const float*)d_in[8];
    const float* U2v = (const float*)d_in[9];
    const float* U3v = (const float*)d_in[10];
    const float* W1v = (const float*)d_in[11];
    const float* W2v = (const float*)d_in[12];
    const float* W3v = (const float*)d_in[13];
    float* out = (float*)d_out;

    int*   cnt  = (int*)d_ws;
    int*   list = (int*)((char*)d_ws + 64);
    float* usym = (float*)((char*)d_ws + 64 + B_N * E_N * 4);   // 163904, 16B-aligned

    hipMemsetAsync(d_ws, 0, 64, stream);
    build_lists_kernel<<<dim3(16), dim3(256), 0, stream>>>(y, cnt, list);
    sym_u_kernel<<<dim3((USYM_FLOATS + 255) / 256), dim3(256), 0, stream>>>(
        U3s, U2s, U3v, U2v, usym);
    sc_main_kernel<<<dim3(128, 10, 8), dim3(256), 0, stream>>>(
        x, cnt, list, usym,
        U1s, U1v, W1s, W2s, W3s, W1v, W2v, W3v,
        out);
}

// Round 3
// 776.459 us; speedup vs baseline: 1.2044x; 1.2044x over previous
//
#include <hip/hip_runtime.h>

#define B_N 4096
#define C_N 128
#define E_N 10

#define NM3 165
#define NM2 45

// Usym float-offsets (relative to usym base in ws)
#define OFF_S3 0        // [165][23]
#define OFF_V3 3795     // [165][3][15]
#define OFF_S2 11220    // [45][3]
#define OFF_V2 11355    // [45][12]
#define USYM_FLOATS 11895

__device__ __forceinline__ void unrank3(int m, int& I, int& J, int& K) {
    int n = 0;
    for (int i = 0; i < 9; ++i)
        for (int j = i; j < 9; ++j)
            for (int k = j; k < 9; ++k) {
                if (n == m) { I = i; J = j; K = k; return; }
                ++n;
            }
}
__device__ __forceinline__ void unrank2(int m, int& I, int& J) {
    int n = 0;
    for (int i = 0; i < 9; ++i)
        for (int j = i; j < 9; ++j) {
            if (n == m) { I = i; J = j; return; }
            ++n;
        }
}

// ---------------------------------------------------------------------------
// Kernel 1: bucket nodes by element (y one-hot over E=10).
// ws: cnt[10] @0 (zeroed each call), list[10*4096] @ byte 64.
// ---------------------------------------------------------------------------
__global__ __launch_bounds__(256) void build_lists_kernel(
    const float* __restrict__ y, int* __restrict__ cnt, int* __restrict__ list)
{
    int b = blockIdx.x * 256 + threadIdx.x;
    if (b >= B_N) return;
    const float* yb = y + (size_t)b * E_N;
    int e = 0;
#pragma unroll
    for (int j = 1; j < E_N; ++j) e = (yb[j] > 0.5f) ? j : e;
    int pos = atomicAdd(&cnt[e], 1);
    list[e * B_N + pos] = b;
}

// ---------------------------------------------------------------------------
// Kernel 2: symmetrize U tensors into monomial basis (e,c-independent).
// Only the symmetric part of U3/U2 contributes to the polynomial.
// ---------------------------------------------------------------------------
__global__ __launch_bounds__(256) void sym_u_kernel(
    const float* __restrict__ U3s, const float* __restrict__ U2s,
    const float* __restrict__ U3v, const float* __restrict__ U2v,
    float* __restrict__ us)
{
    int t = blockIdx.x * 256 + threadIdx.x;
    if (t < 3795) {                      // S3: [165][23]
        int m = t / 23, kk = t - m * 23;
        int i, j, k; unrank3(m, i, j, k);
        float sc = (i == k) ? (1.f / 6.f) : ((i == j || j == k) ? 0.5f : 1.f);
#define U3S(a,b,cc) U3s[(((a)*9+(b))*9+(cc))*23 + kk]
        float v = U3S(i,j,k) + U3S(i,k,j) + U3S(j,i,k) + U3S(j,k,i) + U3S(k,i,j) + U3S(k,j,i);
        us[OFF_S3 + m * 23 + kk] = v * sc;
    } else if (t < 11220) {              // V3: [165][3][15]
        int r = t - 3795;
        int m = r / 45, q = r - m * 45;
        int a = q / 15, kk = q - a * 15;
        int i, j, k; unrank3(m, i, j, k);
        float sc = (i == k) ? (1.f / 6.f) : ((i == j || j == k) ? 0.5f : 1.f);
#define U3V(p,b,cc) U3v[((((a)*9+(p))*9+(b))*9+(cc))*15 + kk]
        float v = U3V(i,j,k) + U3V(i,k,j) + U3V(j,i,k) + U3V(j,k,i) + U3V(k,i,j) + U3V(k,j,i);
        us[OFF_V3 + m * 45 + a * 15 + kk] = v * sc;
    } else if (t < 11355) {              // S2: [45][3]
        int r = t - 11220;
        int m = r / 3, kk = r - m * 3;
        int i, j; unrank2(m, i, j);
        float sc = (i == j) ? 0.5f : 1.f;
        float v = (U2s[(i * 9 + j) * 3 + kk] + U2s[(j * 9 + i) * 3 + kk]) * sc;
        us[OFF_S2 + m * 3 + kk] = v;
    } else if (t < USYM_FLOATS) {        // V2: [45][12]
        int r = t - 11355;
        int m = r / 12, q = r - m * 12;
        int a = q / 4, kk = q - a * 4;
        int i, j; unrank2(m, i, j);
        float sc = (i == j) ? 0.5f : 1.f;
        float v = (U2v[((a * 9 + i) * 9 + j) * 4 + kk] + U2v[((a * 9 + j) * 9 + i) * 4 + kk]) * sc;
        us[OFF_V2 + m * 12 + a * 4 + kk] = v;
    }
}

#define FMA4(acc, t, s) { acc.x = fmaf((t).x, (s), acc.x); acc.y = fmaf((t).y, (s), acc.y); \
                          acc.z = fmaf((t).z, (s), acc.z); acc.w = fmaf((t).w, (s), acc.w); }

// ---------------------------------------------------------------------------
// Kernel 3: main contraction. Block = (channel c, element e, chunk of 512
// nodes). Build 219 float4 monomial coefficients in LDS (one ds_read_b128
// broadcast feeds 8 FMAs), each thread evaluates the degree-3 polynomial for
// 2 nodes. sched_barrier(0) per (i,j) group keeps <=10 float4 LDS loads in
// flight (R2: without fences the scheduler hoisted all 219 loads -> 256 VGPR
// + 1.3 GB scratch spill traffic).
// ---------------------------------------------------------------------------
__global__ __launch_bounds__(256, 4) void sc_main_kernel(
    const float* __restrict__ x,
    const int* __restrict__ cnt, const int* __restrict__ list,
    const float* __restrict__ usym,
    const float* __restrict__ U1s, const float* __restrict__ U1v,
    const float* __restrict__ W1s, const float* __restrict__ W2s, const float* __restrict__ W3s,
    const float* __restrict__ W1v, const float* __restrict__ W2v, const float* __restrict__ W3v,
    float* __restrict__ out)
{
    const int c     = blockIdx.x;   // 0..127
    const int e     = blockIdx.y;   // 0..9
    const int chunk = blockIdx.z;   // 0..7  (512 nodes per block)

    const int n = cnt[e];
    if (chunk * 512 >= n) return;   // uniform early exit

    __shared__ float4 Tm3[NM3];
    __shared__ float4 Tm2[NM2];
    __shared__ float4 Tm1[9];

    const int tid = threadIdx.x;

    // ---- build monomial coefficient tables: Tm = sum_k Usym[m,k] * W[e,k,c]
    if (tid < NM3) {
        const int m = tid;
        float4 t;
        {
            const float* u = usym + OFF_S3 + m * 23;
            float s = 0.f;
#pragma unroll
            for (int k = 0; k < 23; ++k) s = fmaf(u[k], W3s[(e * 23 + k) * C_N + c], s);
            t.x = s;
        }
        float tv[3];
#pragma unroll
        for (int a = 0; a < 3; ++a) {
            const float* u = usym + OFF_V3 + m * 45 + a * 15;
            float s = 0.f;
#pragma unroll
            for (int k = 0; k < 15; ++k) s = fmaf(u[k], W3v[(e * 15 + k) * C_N + c], s);
            tv[a] = s;
        }
        t.y = tv[0]; t.z = tv[1]; t.w = tv[2];
        Tm3[m] = t;
    } else if (tid < NM3 + NM2) {
        const int m = tid - NM3;
        float4 t;
        {
            const float* u = usym + OFF_S2 + m * 3;
            float s = 0.f;
#pragma unroll
            for (int k = 0; k < 3; ++k) s = fmaf(u[k], W2s[(e * 3 + k) * C_N + c], s);
            t.x = s;
        }
        float tv[3];
#pragma unroll
        for (int a = 0; a < 3; ++a) {
            const float* u = usym + OFF_V2 + m * 12 + a * 4;
            float s = 0.f;
#pragma unroll
            for (int k = 0; k < 4; ++k) s = fmaf(u[k], W2v[(e * 4 + k) * C_N + c], s);
            tv[a] = s;
        }
        t.y = tv[0]; t.z = tv[1]; t.w = tv[2];
        Tm2[m] = t;
    } else if (tid < NM3 + NM2 + 9) {
        const int i = tid - (NM3 + NM2);
        float4 t;
        t.x = U1s[i]         * W1s[e * C_N + c];
        t.y = U1v[0 * 9 + i] * W1v[e * C_N + c];
        t.z = U1v[1 * 9 + i] * W1v[e * C_N + c];
        t.w = U1v[2 * 9 + i] * W1v[e * C_N + c];
        Tm1[i] = t;
    }

    __syncthreads();

    const int idx0 = chunk * 512 + tid;
    if (idx0 >= n) return;          // no execution barriers after this point
    const int idx1 = idx0 + 256;
    const bool p1 = idx1 < n;

    const int b0 = list[e * B_N + idx0];
    const int b1 = p1 ? list[e * B_N + idx1] : b0;

    const float* xp0 = x + ((size_t)b0 * C_N + c) * 9;
    const float* xp1 = x + ((size_t)b1 * C_N + c) * 9;
    float x0[9], x1[9];
#pragma unroll
    for (int i = 0; i < 9; ++i) { x0[i] = xp0[i]; x1[i] = xp1[i]; }

    float4 a0 = make_float4(0.f, 0.f, 0.f, 0.f);
    float4 a1 = make_float4(0.f, 0.f, 0.f, 0.f);

    // degree 1
#pragma unroll
    for (int i = 0; i < 9; ++i) {
        float4 t = Tm1[i];
        FMA4(a0, t, x0[i]);
        FMA4(a1, t, x1[i]);
    }
    __builtin_amdgcn_sched_barrier(0);

    // degree 2 + degree 3, triangular, fully unrolled (m2/m3 compile-time).
    // One sched_barrier per (i,j) group: <=10 ds_read_b128 in flight.
    int m2 = 0, m3 = 0;
#pragma unroll
    for (int i = 0; i < 9; ++i) {
#pragma unroll
        for (int j = i; j < 9; ++j) {
            float xij0 = x0[i] * x0[j];
            float xij1 = x1[i] * x1[j];
            float4 t2 = Tm2[m2++];
            FMA4(a0, t2, xij0);
            FMA4(a1, t2, xij1);
#pragma unroll
            for (int k = j; k < 9; ++k) {
                float q0 = xij0 * x0[k];
                float q1 = xij1 * x1[k];
                float4 t3 = Tm3[m3++];
                FMA4(a0, t3, q0);
                FMA4(a1, t3, q1);
            }
            __builtin_amdgcn_sched_barrier(0);
        }
    }

    {
        float* o = out + (size_t)b0 * 512;
        o[c] = a0.x;
        o[128 + c * 3 + 0] = a0.y;
        o[128 + c * 3 + 1] = a0.z;
        o[128 + c * 3 + 2] = a0.w;
    }
    if (p1) {
        float* o = out + (size_t)b1 * 512;
        o[c] = a1.x;
        o[128 + c * 3 + 0] = a1.y;
        o[128 + c * 3 + 1] = a1.z;
        o[128 + c * 3 + 2] = a1.w;
    }
}

// ---------------------------------------------------------------------------
extern "C" void kernel_launch(void* const* d_in, const int* in_sizes, int n_in,
                              void* d_out, int out_size, void* d_ws, size_t ws_size,
                              hipStream_t stream) {
    const float* x   = (const float*)d_in[0];
    const float* y   = (const float*)d_in[1];
    const float* U1s = (const float*)d_in[2];
    const float* U2s = (const float*)d_in[3];
    const float* U3s = (const float*)d_in[4];
    const float* W1s = (const float*)d_in[5];
    const float* W2s = (const float*)d_in[6];
    const float* W3s = (const float*)d_in[7];
    const float* U1v = (const float*)d_in[8];
    const float* U2v = (const float*)d_in[9];
    const float* U3v = (const float*)d_in[10];
    const float* W1v = (const float*)d_in[11];
    const float* W2v = (const float*)d_in[12];
    const float* W3v = (const float*)d_in[13];
    float* out = (float*)d_out;

    int*   cnt  = (int*)d_ws;
    int*   list = (int*)((char*)d_ws + 64);
    float* usym = (float*)((char*)d_ws + 64 + B_N * E_N * 4);   // 16B-aligned

    hipMemsetAsync(d_ws, 0, 64, stream);
    build_lists_kernel<<<dim3(16), dim3(256), 0, stream>>>(y, cnt, list);
    sym_u_kernel<<<dim3((USYM_FLOATS + 255) / 256), dim3(256), 0, stream>>>(
        U3s, U2s, U3v, U2v, usym);
    sc_main_kernel<<<dim3(128, 10, 8), dim3(256), 0, stream>>>(
        x, cnt, list, usym,
        U1s, U1v, W1s, W2s, W3s, W1v, W2v, W3v,
        out);
}

// Round 4
// 98.125 us; speedup vs baseline: 9.5302x; 7.9130x over previous
//
#include <hip/hip_runtime.h>

#define B_N 4096
#define C_N 128
#define E_N 10

#define NM3 165
#define NM2 45
#define NMT 219           // 9 + 45 + 165
#define TSTRIDE 224       // float4 stride per (e,c) table (3584 B, 64B-multiple)

// Usym float-offsets (relative to usym base in ws)
#define OFF_S3 0          // [165][23]
#define OFF_V3 3795       // [165][3][15]
#define OFF_S2 11220      // [45][3]
#define OFF_V2 11355      // [45][12]
#define USYM_FLOATS 11895

// ws byte offsets
#define WS_CNT    0
#define WS_LIST   64
#define WS_USYM   (64 + B_N * E_N * 4)            // 163904
#define WS_TABLES 212992                           // 1024-aligned
// tables bytes: 1280 * 224 * 16 = 4,587,520

__device__ __forceinline__ void unrank3(int m, int& I, int& J, int& K) {
    int n = 0;
    for (int i = 0; i < 9; ++i)
        for (int j = i; j < 9; ++j)
            for (int k = j; k < 9; ++k) {
                if (n == m) { I = i; J = j; K = k; return; }
                ++n;
            }
}
__device__ __forceinline__ void unrank2(int m, int& I, int& J) {
    int n = 0;
    for (int i = 0; i < 9; ++i)
        for (int j = i; j < 9; ++j) {
            if (n == m) { I = i; J = j; return; }
            ++n;
        }
}

// ---------------------------------------------------------------------------
// Kernel 1: bucket nodes by element (y one-hot over E=10).
// ---------------------------------------------------------------------------
__global__ __launch_bounds__(256) void build_lists_kernel(
    const float* __restrict__ y, int* __restrict__ cnt, int* __restrict__ list)
{
    int b = blockIdx.x * 256 + threadIdx.x;
    if (b >= B_N) return;
    const float* yb = y + (size_t)b * E_N;
    int e = 0;
#pragma unroll
    for (int j = 1; j < E_N; ++j) e = (yb[j] > 0.5f) ? j : e;
    int pos = atomicAdd(&cnt[e], 1);
    list[e * B_N + pos] = b;
}

// ---------------------------------------------------------------------------
// Kernel 2: symmetrize U tensors into monomial basis (e,c-independent).
// ---------------------------------------------------------------------------
__global__ __launch_bounds__(256) void sym_u_kernel(
    const float* __restrict__ U3s, const float* __restrict__ U2s,
    const float* __restrict__ U3v, const float* __restrict__ U2v,
    float* __restrict__ us)
{
    int t = blockIdx.x * 256 + threadIdx.x;
    if (t < 3795) {                      // S3: [165][23]
        int m = t / 23, kk = t - m * 23;
        int i, j, k; unrank3(m, i, j, k);
        float sc = (i == k) ? (1.f / 6.f) : ((i == j || j == k) ? 0.5f : 1.f);
#define U3S(a,b,cc) U3s[(((a)*9+(b))*9+(cc))*23 + kk]
        float v = U3S(i,j,k) + U3S(i,k,j) + U3S(j,i,k) + U3S(j,k,i) + U3S(k,i,j) + U3S(k,j,i);
        us[OFF_S3 + m * 23 + kk] = v * sc;
    } else if (t < 11220) {              // V3: [165][3][15]
        int r = t - 3795;
        int m = r / 45, q = r - m * 45;
        int a = q / 15, kk = q - a * 15;
        int i, j, k; unrank3(m, i, j, k);
        float sc = (i == k) ? (1.f / 6.f) : ((i == j || j == k) ? 0.5f : 1.f);
#define U3V(p,b,cc) U3v[((((a)*9+(p))*9+(b))*9+(cc))*15 + kk]
        float v = U3V(i,j,k) + U3V(i,k,j) + U3V(j,i,k) + U3V(j,k,i) + U3V(k,i,j) + U3V(k,j,i);
        us[OFF_V3 + m * 45 + a * 15 + kk] = v * sc;
    } else if (t < 11355) {              // S2: [45][3]
        int r = t - 11220;
        int m = r / 3, kk = r - m * 3;
        int i, j; unrank2(m, i, j);
        float sc = (i == j) ? 0.5f : 1.f;
        us[OFF_S2 + m * 3 + kk] =
            (U2s[(i * 9 + j) * 3 + kk] + U2s[(j * 9 + i) * 3 + kk]) * sc;
    } else if (t < USYM_FLOATS) {        // V2: [45][12]
        int r = t - 11355;
        int m = r / 12, q = r - m * 12;
        int a = q / 4, kk = q - a * 4;
        int i, j; unrank2(m, i, j);
        float sc = (i == j) ? 0.5f : 1.f;
        us[OFF_V2 + m * 12 + a * 4 + kk] =
            (U2v[((a * 9 + i) * 9 + j) * 4 + kk] + U2v[((a * 9 + j) * 9 + i) * 4 + kk]) * sc;
    }
}

// ---------------------------------------------------------------------------
// Kernel 3: build per-(e,c) monomial coefficient tables in GLOBAL ws.
// Table[(e*128+c)*224 + m] = float4(s, v0, v1, v2); m: 0..8 deg1, 9..53 deg2,
// 54..218 deg3 (lexicographic triangular order = main kernel's walk order).
// ---------------------------------------------------------------------------
__global__ __launch_bounds__(256) void build_tables_kernel(
    const float* __restrict__ usym,
    const float* __restrict__ U1s, const float* __restrict__ U1v,
    const float* __restrict__ W1s, const float* __restrict__ W2s, const float* __restrict__ W3s,
    const float* __restrict__ W1v, const float* __restrict__ W2v, const float* __restrict__ W3v,
    float* __restrict__ tables)
{
    const int c = blockIdx.x;   // 0..127
    const int e = blockIdx.y;   // 0..9
    const int m = threadIdx.x;
    if (m >= NMT) return;

    float4 t;
    if (m < 9) {
        const int i = m;
        t.x = U1s[i]      * W1s[e * C_N + c];
        t.y = U1v[i]      * W1v[e * C_N + c];
        t.z = U1v[9 + i]  * W1v[e * C_N + c];
        t.w = U1v[18 + i] * W1v[e * C_N + c];
    } else if (m < 9 + NM2) {
        const int mm = m - 9;
        float s = 0.f;
#pragma unroll
        for (int k = 0; k < 3; ++k)
            s = fmaf(usym[OFF_S2 + mm * 3 + k], W2s[(e * 3 + k) * C_N + c], s);
        t.x = s;
        float tv[3];
#pragma unroll
        for (int a = 0; a < 3; ++a) {
            float sv = 0.f;
#pragma unroll
            for (int k = 0; k < 4; ++k)
                sv = fmaf(usym[OFF_V2 + mm * 12 + a * 4 + k], W2v[(e * 4 + k) * C_N + c], sv);
            tv[a] = sv;
        }
        t.y = tv[0]; t.z = tv[1]; t.w = tv[2];
    } else {
        const int mm = m - (9 + NM2);
        float s = 0.f;
#pragma unroll
        for (int k = 0; k < 23; ++k)
            s = fmaf(usym[OFF_S3 + mm * 23 + k], W3s[(e * 23 + k) * C_N + c], s);
        t.x = s;
        float tv[3];
#pragma unroll
        for (int a = 0; a < 3; ++a) {
            float sv = 0.f;
#pragma unroll
            for (int k = 0; k < 15; ++k)
                sv = fmaf(usym[OFF_V3 + mm * 45 + a * 15 + k], W3v[(e * 15 + k) * C_N + c], sv);
            tv[a] = sv;
        }
        t.y = tv[0]; t.z = tv[1]; t.w = tv[2];
    }
    ((float4*)tables)[(size_t)(e * C_N + c) * TSTRIDE + m] = t;
}

#define FMA4(acc, t, s) { acc.x = fmaf((t).x, (s), acc.x); acc.y = fmaf((t).y, (s), acc.y); \
                          acc.z = fmaf((t).z, (s), acc.z); acc.w = fmaf((t).w, (s), acc.w); }

// ---------------------------------------------------------------------------
// Kernel 4: main contraction. One thread = one (node, channel). Coefficient
// table address is block-uniform with compile-time offsets -> every T[m]
// becomes an s_load into SGPRs (no VGPR pressure, no LDS, no fences).
// ---------------------------------------------------------------------------
__global__ __launch_bounds__(256, 4) void sc_main_kernel(
    const float* __restrict__ x,
    const int* __restrict__ cnt, const int* __restrict__ list,
    const float* __restrict__ tables,
    float* __restrict__ out)
{
    const int c     = blockIdx.x;   // 0..127
    const int e     = blockIdx.y;   // 0..9
    const int chunk = blockIdx.z;   // 0..15

    const int n   = cnt[e];
    const int idx = chunk * 256 + threadIdx.x;
    if (idx >= n) return;
    const int b = list[e * B_N + idx];

    const float4* __restrict__ T =
        (const float4*)tables + (size_t)(e * C_N + c) * TSTRIDE;   // block-uniform

    const float* xp = x + ((size_t)b * C_N + c) * 9;
    float xr[9];
#pragma unroll
    for (int i = 0; i < 9; ++i) xr[i] = xp[i];

    float4 acc = make_float4(0.f, 0.f, 0.f, 0.f);

    // degree 1: m = 0..8
#pragma unroll
    for (int i = 0; i < 9; ++i) {
        float4 t = T[i];
        FMA4(acc, t, xr[i]);
    }

    // degree 2 (m=9..53) + degree 3 (m=54..218), lexicographic triangular,
    // fully unrolled -> all indices compile-time.
    int m2 = 9, m3 = 9 + NM2;
#pragma unroll
    for (int i = 0; i < 9; ++i) {
#pragma unroll
        for (int j = i; j < 9; ++j) {
            float xij = xr[i] * xr[j];
            float4 t2 = T[m2++];
            FMA4(acc, t2, xij);
#pragma unroll
            for (int k = j; k < 9; ++k) {
                float q = xij * xr[k];
                float4 t3 = T[m3++];
                FMA4(acc, t3, q);
            }
        }
    }

    float* o = out + (size_t)b * 512;
    o[c] = acc.x;
    o[128 + c * 3 + 0] = acc.y;
    o[128 + c * 3 + 1] = acc.z;
    o[128 + c * 3 + 2] = acc.w;
}

// ---------------------------------------------------------------------------
extern "C" void kernel_launch(void* const* d_in, const int* in_sizes, int n_in,
                              void* d_out, int out_size, void* d_ws, size_t ws_size,
                              hipStream_t stream) {
    const float* x   = (const float*)d_in[0];
    const float* y   = (const float*)d_in[1];
    const float* U1s = (const float*)d_in[2];
    const float* U2s = (const float*)d_in[3];
    const float* U3s = (const float*)d_in[4];
    const float* W1s = (const float*)d_in[5];
    const float* W2s = (const float*)d_in[6];
    const float* W3s = (const float*)d_in[7];
    const float* U1v = (const float*)d_in[8];
    const float* U2v = (const float*)d_in[9];
    const float* U3v = (const float*)d_in[10];
    const float* W1v = (const float*)d_in[11];
    const float* W2v = (const float*)d_in[12];
    const float* W3v = (const float*)d_in[13];
    float* out = (float*)d_out;

    int*   cnt    = (int*)((char*)d_ws + WS_CNT);
    int*   list   = (int*)((char*)d_ws + WS_LIST);
    float* usym   = (float*)((char*)d_ws + WS_USYM);
    float* tables = (float*)((char*)d_ws + WS_TABLES);

    hipMemsetAsync(d_ws, 0, 64, stream);
    build_lists_kernel<<<dim3(16), dim3(256), 0, stream>>>(y, cnt, list);
    sym_u_kernel<<<dim3((USYM_FLOATS + 255) / 256), dim3(256), 0, stream>>>(
        U3s, U2s, U3v, U2v, usym);
    build_tables_kernel<<<dim3(128, 10), dim3(256), 0, stream>>>(
        usym, U1s, U1v, W1s, W2s, W3s, W1v, W2v, W3v, tables);
    sc_main_kernel<<<dim3(128, 10, 16), dim3(256), 0, stream>>>(
        x, cnt, list, tables, out);
}